// Round 1
// baseline (950.527 us; speedup 1.0000x reference)
//
#include <hip/hip_runtime.h>
#include <stdint.h>

// Problem constants
#define B_      64
#define N_TOK   577
#define C_      768
#define H_      12
#define BH_     768      // B_*H_
#define M_ROWS  36928    // B_*N_TOK
#define M_PAD   36992    // 289 * 128
#define KEEP    289      // kept keys incl CLS
#define KP      320      // padded key count (20 * 16)
#define QKV_N   2304

typedef __attribute__((ext_vector_type(8))) short   bf16x8;
typedef __attribute__((ext_vector_type(4))) float   floatx4;
typedef __attribute__((ext_vector_type(4))) short   short4v;

static __device__ __forceinline__ unsigned short f2bf(float f) {
  union { float f; unsigned u; } a; a.f = f;
  unsigned u = a.u;
  u = u + 0x7FFFu + ((u >> 16) & 1u);   // RNE; inputs are finite, no NaN handling needed
  return (unsigned short)(u >> 16);
}

static __device__ __forceinline__ void gl_lds16(const void* g, void* l) {
  __builtin_amdgcn_global_load_lds(
      (const __attribute__((address_space(1))) void*)g,
      (__attribute__((address_space(3))) void*)l, 16, 0, 0);
}

// ---------------------------------------------------------------------------
// 1. top-k(288) per (b,h) row of mask[768][576] -> pos[768][577]
//    pos[t] = slot in kept list (0=CLS, ascending token order), -1 if dropped.
//    Tie-break identical to jax.lax.top_k: strictly-greater OR equal-with-lower-index.
__global__ void topk_kernel(const float* __restrict__ mask, int* __restrict__ pos) {
  __shared__ float vals[576];
  __shared__ int woff[9];
  int row = blockIdx.x;
  int t = threadIdx.x;
  float v = mask[(size_t)row * 576 + t];
  vals[t] = v;
  __syncthreads();
  int rank = 0;
  for (int j = 0; j < 576; ++j) {
    float u = vals[j];
    rank += ((u > v) || (u == v && j < t)) ? 1 : 0;
  }
  bool sel = rank < (KEEP - 1);
  unsigned long long ball = __ballot(sel ? 1 : 0);
  int lane = t & 63, w = t >> 6;
  int lp = __popcll(ball & ((1ull << lane) - 1ull));
  if (lane == 0) woff[w] = __popcll(ball);
  __syncthreads();
  int base = 0;
  for (int i = 0; i < w; ++i) base += woff[i];
  pos[(size_t)row * 577 + 1 + t] = sel ? (1 + base + lp) : -1;
  if (t == 0) pos[(size_t)row * 577] = 0;
}

// ---------------------------------------------------------------------------
// 2. x fp32 -> bf16, padded rows [36928..36992) zeroed
__global__ void convx_kernel(const float* __restrict__ x, unsigned short* __restrict__ xb) {
  size_t i = ((size_t)blockIdx.x * 256 + threadIdx.x) * 4;
  short4v o;
  if (i < (size_t)M_ROWS * C_) {
    float4 v = *(const float4*)(x + i);
    o.x = (short)f2bf(v.x); o.y = (short)f2bf(v.y);
    o.z = (short)f2bf(v.z); o.w = (short)f2bf(v.w);
  } else {
    o.x = 0; o.y = 0; o.z = 0; o.w = 0;
  }
  *(short4v*)(xb + i) = o;
}

// 3. W [K][N] fp32 -> Wt [N][K] bf16   (K=768)
__global__ void convwT_kernel(const float* __restrict__ W, unsigned short* __restrict__ Wt,
                              int K, int N) {
  size_t idx = (size_t)blockIdx.x * 256 + threadIdx.x;
  if (idx >= (size_t)K * N) return;
  int n = (int)(idx / K), k = (int)(idx % K);
  Wt[idx] = f2bf(W[(size_t)k * N + n]);
}

// 4. zero pad rows [289..320) of Kp and Vp
__global__ void zeropad_kernel(unsigned short* __restrict__ Kp, unsigned short* __restrict__ Vp) {
  size_t idx = (size_t)blockIdx.x * 256 + threadIdx.x;  // 768*31*64 exact
  int bh = (int)(idx / (31 * 64));
  int rem = (int)(idx % (31 * 64));
  int r = KEEP + rem / 64, d = rem & 63;
  size_t o = ((size_t)bh * KP + r) * 64 + d;
  Kp[o] = 0; Vp[o] = 0;
}

// ---------------------------------------------------------------------------
// 5. QKV GEMM:  A[M_PAD][768] bf16 x WqkvT[2304][768] bf16 -> scatter Q/Kp/Vp bf16
//    128x128 tile, BK=32, 4 waves (2x2), 4x4 16x16x32 MFMA per wave, global_load_lds.
__global__ __launch_bounds__(256) void qkv_gemm_kernel(
    const unsigned short* __restrict__ A, const unsigned short* __restrict__ Bt,
    const float* __restrict__ bias, const int* __restrict__ pos,
    unsigned short* __restrict__ Q, unsigned short* __restrict__ Kp,
    unsigned short* __restrict__ Vp) {
  __shared__ unsigned short As[128 * 32];
  __shared__ unsigned short Bs[128 * 32];
  const int tid = threadIdx.x;
  const int lane = tid & 63, wv = tid >> 6;
  const int quad = lane >> 4, lcol = lane & 15;
  const int wm = wv & 1, wn = wv >> 1;
  const int m0 = blockIdx.y * 128, n0 = blockIdx.x * 128;

  floatx4 acc[4][4] = {};
  for (int k0 = 0; k0 < 768; k0 += 32) {
    for (int c = 0; c < 2; ++c) {
      int s = c * 256 + tid;
      int r = s >> 2, kk = (s & 3) << 3;
      gl_lds16(A  + (size_t)(m0 + r) * 768 + k0 + kk, As + s * 8);
      gl_lds16(Bt + (size_t)(n0 + r) * 768 + k0 + kk, Bs + s * 8);
    }
    __syncthreads();
    bf16x8 af[4], bfr[4];
    for (int i = 0; i < 4; ++i)
      af[i] = *(const bf16x8*)(As + (wm * 64 + i * 16 + lcol) * 32 + quad * 8);
    for (int i = 0; i < 4; ++i)
      bfr[i] = *(const bf16x8*)(Bs + (wn * 64 + i * 16 + lcol) * 32 + quad * 8);
    for (int i = 0; i < 4; ++i)
      for (int j = 0; j < 4; ++j)
        acc[i][j] = __builtin_amdgcn_mfma_f32_16x16x32_bf16(af[i], bfr[j], acc[i][j], 0, 0, 0);
    __syncthreads();
  }
  // epilogue: col n = which*768 + h*64 + d ; row m = b*577 + t
  for (int mt = 0; mt < 4; ++mt) {
    for (int r = 0; r < 4; ++r) {
      int m = m0 + wm * 64 + mt * 16 + quad * 4 + r;
      if (m >= M_ROWS) continue;
      int b = m / 577, t = m - b * 577;
      for (int nt = 0; nt < 4; ++nt) {
        int n = n0 + wn * 64 + nt * 16 + lcol;
        float v = acc[mt][nt][r] + bias[n];
        unsigned short hv = f2bf(v);
        int which = n / 768, rem = n - which * 768;
        int h = rem >> 6, d = rem & 63;
        int bh = b * 12 + h;
        if (which == 0) {
          Q[((size_t)bh * 577 + t) * 64 + d] = hv;
        } else {
          int p = pos[(size_t)bh * 577 + t];
          if (p >= 0) {
            size_t o = ((size_t)bh * KP + p) * 64 + d;
            if (which == 1) Kp[o] = hv; else Vp[o] = hv;
          }
        }
      }
    }
  }
}

// 6. Vp[bh][320][64] -> VpT[bh][64][320]
__global__ void transv_kernel(const unsigned short* __restrict__ Vp,
                              unsigned short* __restrict__ VpT) {
  size_t idx = (size_t)blockIdx.x * 256 + threadIdx.x;  // BH_*64*320 exact
  int bh = (int)(idx / (64 * KP));
  int rem = (int)(idx % (64 * KP));
  int d = rem / KP, p = rem % KP;
  VpT[idx] = Vp[((size_t)bh * KP + p) * 64 + d];
}

// ---------------------------------------------------------------------------
// 7. Attention: per (q-tile of 64, bh). S in registers, register softmax, P->LDS,
//    PV from LDS(A) + global VpT(B). Output scattered into attnout[M_PAD][768].
__global__ __launch_bounds__(256) void attn_kernel(
    const unsigned short* __restrict__ Q, const unsigned short* __restrict__ Kp,
    const unsigned short* __restrict__ VpT, unsigned short* __restrict__ attnout) {
  __shared__ unsigned short P[64 * 328];   // stride 328: 656B = 164 dwords = +4 mod 32 banks
  const int tid = threadIdx.x;
  const int lane = tid & 63, w = tid >> 6;
  const int quad = lane >> 4, lcol = lane & 15;
  const int bx = blockIdx.x, by = blockIdx.y;
  const int q0 = bx * 64 + w * 16;

  bf16x8 aq[2];
  {
    int qr = q0 + lcol;
    if (qr < N_TOK) {
      const unsigned short* qp = Q + ((size_t)by * N_TOK + qr) * 64;
      aq[0] = *(const bf16x8*)(qp + quad * 8);
      aq[1] = *(const bf16x8*)(qp + 32 + quad * 8);
    } else {
      bf16x8 z = {0, 0, 0, 0, 0, 0, 0, 0};
      aq[0] = z; aq[1] = z;
    }
  }
  floatx4 sacc[20] = {};
  for (int nt = 0; nt < 20; ++nt) {
    const unsigned short* kp = Kp + ((size_t)by * KP + nt * 16 + lcol) * 64;
    bf16x8 b0 = *(const bf16x8*)(kp + quad * 8);
    bf16x8 b1 = *(const bf16x8*)(kp + 32 + quad * 8);
    sacc[nt] = __builtin_amdgcn_mfma_f32_16x16x32_bf16(aq[0], b0, sacc[nt], 0, 0, 0);
    sacc[nt] = __builtin_amdgcn_mfma_f32_16x16x32_bf16(aq[1], b1, sacc[nt], 0, 0, 0);
  }
  const float scale = 0.125f;  // 64^-0.5
  for (int r = 0; r < 4; ++r) {
    float mx = -1e30f;
    for (int nt = 0; nt < 20; ++nt) {
      int n = nt * 16 + lcol;
      float s = sacc[nt][r] * scale;
      if (n < KEEP) mx = fmaxf(mx, s);
    }
    for (int off = 1; off < 16; off <<= 1) mx = fmaxf(mx, __shfl_xor(mx, off, 64));
    float sum = 0.f;
    for (int nt = 0; nt < 20; ++nt) {
      int n = nt * 16 + lcol;
      float e = (n < KEEP) ? __expf(sacc[nt][r] * scale - mx) : 0.f;
      sacc[nt][r] = e;
      sum += e;
    }
    for (int off = 1; off < 16; off <<= 1) sum += __shfl_xor(sum, off, 64);
    float inv = 1.f / sum;
    int rowl = w * 16 + quad * 4 + r;
    for (int nt = 0; nt < 20; ++nt)
      P[rowl * 328 + nt * 16 + lcol] = f2bf(sacc[nt][r] * inv);
  }
  __syncthreads();
  floatx4 oacc[4] = {};
  for (int kc = 0; kc < 10; ++kc) {
    bf16x8 pa = *(const bf16x8*)(P + (w * 16 + lcol) * 328 + kc * 32 + quad * 8);
    for (int nt = 0; nt < 4; ++nt) {
      bf16x8 vb = *(const bf16x8*)(VpT + ((size_t)by * 64 + nt * 16 + lcol) * KP + kc * 32 + quad * 8);
      oacc[nt] = __builtin_amdgcn_mfma_f32_16x16x32_bf16(pa, vb, oacc[nt], 0, 0, 0);
    }
  }
  int b = by / H_, h = by - b * H_;
  for (int nt = 0; nt < 4; ++nt)
    for (int r = 0; r < 4; ++r) {
      int qr = bx * 64 + w * 16 + quad * 4 + r;
      if (qr < N_TOK)
        attnout[((size_t)(b * N_TOK + qr)) * C_ + h * 64 + nt * 16 + lcol] = f2bf(oacc[nt][r]);
    }
}

// ---------------------------------------------------------------------------
// 8. Proj GEMM: attnout[M_PAD][768] bf16 x WprojT[768][768] bf16 -> out fp32 + bias
__global__ __launch_bounds__(256) void proj_gemm_kernel(
    const unsigned short* __restrict__ A, const unsigned short* __restrict__ Bt,
    const float* __restrict__ bias, float* __restrict__ out) {
  __shared__ unsigned short As[128 * 32];
  __shared__ unsigned short Bs[128 * 32];
  const int tid = threadIdx.x;
  const int lane = tid & 63, wv = tid >> 6;
  const int quad = lane >> 4, lcol = lane & 15;
  const int wm = wv & 1, wn = wv >> 1;
  const int m0 = blockIdx.y * 128, n0 = blockIdx.x * 128;

  floatx4 acc[4][4] = {};
  for (int k0 = 0; k0 < 768; k0 += 32) {
    for (int c = 0; c < 2; ++c) {
      int s = c * 256 + tid;
      int r = s >> 2, kk = (s & 3) << 3;
      gl_lds16(A  + (size_t)(m0 + r) * 768 + k0 + kk, As + s * 8);
      gl_lds16(Bt + (size_t)(n0 + r) * 768 + k0 + kk, Bs + s * 8);
    }
    __syncthreads();
    bf16x8 af[4], bfr[4];
    for (int i = 0; i < 4; ++i)
      af[i] = *(const bf16x8*)(As + (wm * 64 + i * 16 + lcol) * 32 + quad * 8);
    for (int i = 0; i < 4; ++i)
      bfr[i] = *(const bf16x8*)(Bs + (wn * 64 + i * 16 + lcol) * 32 + quad * 8);
    for (int i = 0; i < 4; ++i)
      for (int j = 0; j < 4; ++j)
        acc[i][j] = __builtin_amdgcn_mfma_f32_16x16x32_bf16(af[i], bfr[j], acc[i][j], 0, 0, 0);
    __syncthreads();
  }
  for (int mt = 0; mt < 4; ++mt)
    for (int r = 0; r < 4; ++r) {
      int m = m0 + wm * 64 + mt * 16 + quad * 4 + r;
      if (m >= M_ROWS) continue;
      for (int nt = 0; nt < 4; ++nt) {
        int n = n0 + wn * 64 + nt * 16 + lcol;
        out[(size_t)m * C_ + n] = acc[mt][nt][r] + bias[n];
      }
    }
}

// ---------------------------------------------------------------------------
extern "C" void kernel_launch(void* const* d_in, const int* in_sizes, int n_in,
                              void* d_out, int out_size, void* d_ws, size_t ws_size,
                              hipStream_t stream) {
  const float* x     = (const float*)d_in[0];
  const float* mask  = (const float*)d_in[1];
  const float* Wqkv  = (const float*)d_in[2];
  const float* bqkv  = (const float*)d_in[3];
  const float* Wproj = (const float*)d_in[4];
  const float* bproj = (const float*)d_in[5];
  float* out = (float*)d_out;

  char* ws = (char*)d_ws;
  // workspace layout (bytes); xb region is reused for attnout after QKV is consumed
  unsigned short* xb     = (unsigned short*)(ws);                  // 56,819,712
  unsigned short* attno  = xb;                                     // reuse (pad rows stay 0)
  unsigned short* WqkvT  = (unsigned short*)(ws + 56819712);       //  3,538,944
  unsigned short* WprojT = (unsigned short*)(ws + 60358656);       //  1,179,648
  int*            pos    = (int*)(ws + 61538304);                  //  1,772,544
  unsigned short* Qb     = (unsigned short*)(ws + 63310848);       // 56,721,408
  unsigned short* Kpb    = (unsigned short*)(ws + 120032256);      // 31,457,280
  unsigned short* Vpb    = (unsigned short*)(ws + 151489536);      // 31,457,280
  unsigned short* VpTb   = (unsigned short*)(ws + 182946816);      // 31,457,280
  // total: 214,404,096 bytes

  hipLaunchKernelGGL(topk_kernel,     dim3(768),      dim3(576), 0, stream, mask, pos);
  hipLaunchKernelGGL(convx_kernel,    dim3(27744),    dim3(256), 0, stream, x, xb);
  hipLaunchKernelGGL(convwT_kernel,   dim3(6912),     dim3(256), 0, stream, Wqkv, WqkvT, 768, 2304);
  hipLaunchKernelGGL(convwT_kernel,   dim3(2304),     dim3(256), 0, stream, Wproj, WprojT, 768, 768);
  hipLaunchKernelGGL(zeropad_kernel,  dim3(5952),     dim3(256), 0, stream, Kpb, Vpb);
  hipLaunchKernelGGL(qkv_gemm_kernel, dim3(18, 289),  dim3(256), 0, stream, xb, WqkvT, bqkv, pos, Qb, Kpb, Vpb);
  hipLaunchKernelGGL(transv_kernel,   dim3(61440),    dim3(256), 0, stream, Vpb, VpTb);
  hipLaunchKernelGGL(attn_kernel,     dim3(10, 768),  dim3(256), 0, stream, Qb, Kpb, VpTb, attno);
  hipLaunchKernelGGL(proj_gemm_kernel,dim3(6, 289),   dim3(256), 0, stream, attno, WprojT, bproj, out);
}

// Round 2
// 798.920 us; speedup vs baseline: 1.1898x; 1.1898x over previous
//
#include <hip/hip_runtime.h>
#include <stdint.h>

// Problem constants
#define B_      64
#define N_TOK   577
#define C_      768
#define H_      12
#define BH_     768      // B_*H_
#define M_ROWS  36928    // B_*N_TOK
#define M_PAD   36992    // 289 * 128
#define KEEP    289      // kept keys incl CLS
#define KP      320      // padded key count (20 * 16)

typedef __attribute__((ext_vector_type(8))) short   bf16x8;
typedef __attribute__((ext_vector_type(4))) float   floatx4;
typedef __attribute__((ext_vector_type(4))) short   short4v;

static __device__ __forceinline__ unsigned short f2bf(float f) {
  union { float f; unsigned u; } a; a.f = f;
  unsigned u = a.u;
  u = u + 0x7FFFu + ((u >> 16) & 1u);   // RNE; finite inputs
  return (unsigned short)(u >> 16);
}

static __device__ __forceinline__ void gl_lds16(const void* g, void* l) {
  __builtin_amdgcn_global_load_lds(
      (const __attribute__((address_space(1))) void*)g,
      (__attribute__((address_space(3))) void*)l, 16, 0, 0);
}

// ---------------------------------------------------------------------------
// 1. top-k(288) per (b,h) row of mask[768][576] -> pos[768][577]
__global__ void topk_kernel(const float* __restrict__ mask, int* __restrict__ pos) {
  __shared__ float vals[576];
  __shared__ int woff[9];
  int row = blockIdx.x;
  int t = threadIdx.x;
  float v = mask[(size_t)row * 576 + t];
  vals[t] = v;
  __syncthreads();
  int rank = 0;
  for (int j = 0; j < 576; ++j) {
    float u = vals[j];
    rank += ((u > v) || (u == v && j < t)) ? 1 : 0;
  }
  bool sel = rank < (KEEP - 1);
  unsigned long long ball = __ballot(sel ? 1 : 0);
  int lane = t & 63, w = t >> 6;
  int lp = __popcll(ball & ((1ull << lane) - 1ull));
  if (lane == 0) woff[w] = __popcll(ball);
  __syncthreads();
  int base = 0;
  for (int i = 0; i < w; ++i) base += woff[i];
  pos[(size_t)row * 577 + 1 + t] = sel ? (1 + base + lp) : -1;
  if (t == 0) pos[(size_t)row * 577] = 0;
}

// ---------------------------------------------------------------------------
// 2. x fp32 -> bf16, padded rows zeroed
__global__ void convx_kernel(const float* __restrict__ x, unsigned short* __restrict__ xb) {
  size_t i = ((size_t)blockIdx.x * 256 + threadIdx.x) * 4;
  short4v o;
  if (i < (size_t)M_ROWS * C_) {
    float4 v = *(const float4*)(x + i);
    o.x = (short)f2bf(v.x); o.y = (short)f2bf(v.y);
    o.z = (short)f2bf(v.z); o.w = (short)f2bf(v.w);
  } else {
    o.x = 0; o.y = 0; o.z = 0; o.w = 0;
  }
  *(short4v*)(xb + i) = o;
}

// 3. W [768][N] fp32 -> Wt [N][768] bf16, tiled 64x64 via LDS (both sides coalesced)
__global__ void convwT_kernel(const float* __restrict__ W, unsigned short* __restrict__ Wt,
                              int N) {
  __shared__ unsigned short tile[64 * 72];
  int n0 = blockIdx.x * 64, k0 = blockIdx.y * 64;
  int t = threadIdx.x;
  for (int p = 0; p < 4; ++p) {           // 64 k-rows x 16 float4 chunks
    int s = p * 256 + t;
    int k = s >> 4, nc = s & 15;
    float4 v = *(const float4*)(W + (size_t)(k0 + k) * N + n0 + nc * 4);
    short4v o;
    o.x = (short)f2bf(v.x); o.y = (short)f2bf(v.y);
    o.z = (short)f2bf(v.z); o.w = (short)f2bf(v.w);
    *(short4v*)(tile + k * 72 + nc * 4) = o;
  }
  __syncthreads();
  for (int p = 0; p < 2; ++p) {           // 64 n-rows x 8 k-chunks of 8
    int s = p * 256 + t;
    int n = s >> 3, kc = s & 7;
    bf16x8 o;
    for (int j = 0; j < 8; ++j) o[j] = (short)tile[(kc * 8 + j) * 72 + n];
    *(bf16x8*)(Wt + (size_t)(n0 + n) * 768 + k0 + kc * 8) = o;
  }
}

// 4. zero pad rows [289..320) of Kp and Vp
__global__ void zeropad_kernel(unsigned short* __restrict__ Kp, unsigned short* __restrict__ Vp) {
  size_t idx = (size_t)blockIdx.x * 256 + threadIdx.x;  // 768*31*64 exact
  int bh = (int)(idx / (31 * 64));
  int rem = (int)(idx % (31 * 64));
  int r = KEEP + rem / 64, d = rem & 63;
  size_t o = ((size_t)bh * KP + r) * 64 + d;
  Kp[o] = 0; Vp[o] = 0;
}

// ---------------------------------------------------------------------------
// 5. QKV GEMM: A[M_PAD][768] x WqkvT[2304][768] -> scatter Q/Kp/Vp bf16.
//    128x128 tile, BK=64, XOR-swizzled LDS, XCD supertile swizzle.
__global__ __launch_bounds__(256) void qkv_gemm_kernel(
    const unsigned short* __restrict__ A, const unsigned short* __restrict__ Bt,
    const float* __restrict__ bias, const int* __restrict__ pos,
    unsigned short* __restrict__ Q, unsigned short* __restrict__ Kp,
    unsigned short* __restrict__ Vp) {
  __shared__ unsigned short As[128 * 64];
  __shared__ unsigned short Bs[128 * 64];
  const int tid = threadIdx.x;
  const int lane = tid & 63, wv = tid >> 6;
  const int quad = lane >> 4, lcol = lane & 15;
  const int wm = wv & 1, wn = wv >> 1;
  // supertile decode: ids sharing m-panel all have id%8 == mi -> same XCD
  int sid = blockIdx.x;
  int m_t, n_t;
  if (sid < 5184) {
    int sb = sid / 48, r = sid % 48;
    int gm = sb % 36, gn = sb / 36;
    m_t = gm * 8 + (r & 7);
    n_t = gn * 6 + (r >> 3);
  } else { m_t = 288; n_t = sid - 5184; }
  const int m0 = m_t * 128, n0 = n_t * 128;
  const int swz = lcol & 7;

  floatx4 acc[4][4] = {};
  for (int k0 = 0; k0 < 768; k0 += 64) {
#pragma unroll
    for (int c = 0; c < 4; ++c) {
      int s = c * 256 + tid;
      int r = s >> 3, cs = s & 7;
      int gc = ((cs ^ (r & 7)) << 3);
      gl_lds16(A  + (size_t)(m0 + r) * 768 + k0 + gc, As + s * 8);
      gl_lds16(Bt + (size_t)(n0 + r) * 768 + k0 + gc, Bs + s * 8);
    }
    __syncthreads();
#pragma unroll
    for (int kh = 0; kh < 2; ++kh) {
      bf16x8 af[4], bfr[4];
      int cc = kh * 4 + quad;
#pragma unroll
      for (int i = 0; i < 4; ++i)
        af[i] = *(const bf16x8*)(As + (wm * 64 + i * 16 + lcol) * 64 + ((cc ^ swz) << 3));
#pragma unroll
      for (int i = 0; i < 4; ++i)
        bfr[i] = *(const bf16x8*)(Bs + (wn * 64 + i * 16 + lcol) * 64 + ((cc ^ swz) << 3));
#pragma unroll
      for (int i = 0; i < 4; ++i)
#pragma unroll
        for (int j = 0; j < 4; ++j)
          acc[i][j] = __builtin_amdgcn_mfma_f32_16x16x32_bf16(af[i], bfr[j], acc[i][j], 0, 0, 0);
    }
    __syncthreads();
  }
  // epilogue: which & h are wave-uniform (64-col span)
  const int nbase = n0 + wn * 64;
  const int which = nbase / 768;
  const int h = (nbase - which * 768) >> 6;
  float bv[4];
#pragma unroll
  for (int nt = 0; nt < 4; ++nt) bv[nt] = bias[nbase + nt * 16 + lcol];
#pragma unroll
  for (int mt = 0; mt < 4; ++mt) {
#pragma unroll
    for (int r = 0; r < 4; ++r) {
      int m = m0 + wm * 64 + mt * 16 + quad * 4 + r;
      if (m >= M_ROWS) continue;
      int b = m / 577, t = m - b * 577;
      int bh = b * 12 + h;
      if (which == 0) {
        size_t base = ((size_t)bh * 577 + t) * 64;
#pragma unroll
        for (int nt = 0; nt < 4; ++nt)
          Q[base + nt * 16 + lcol] = f2bf(acc[mt][nt][r] + bv[nt]);
      } else {
        int p = pos[(size_t)bh * 577 + t];
        if (p >= 0) {
          size_t base = ((size_t)bh * KP + p) * 64;
          unsigned short* dst = (which == 1) ? Kp : Vp;
#pragma unroll
          for (int nt = 0; nt < 4; ++nt)
            dst[base + nt * 16 + lcol] = f2bf(acc[mt][nt][r] + bv[nt]);
        }
      }
    }
  }
}

// 6. Vp[bh][320][64] -> VpT[bh][64][320], tiled 64x64 via LDS
__global__ void transv_kernel(const unsigned short* __restrict__ Vp,
                              unsigned short* __restrict__ VpT) {
  __shared__ unsigned short tile[64 * 72];
  int bh = blockIdx.y, p0 = blockIdx.x * 64;
  int t = threadIdx.x;
  for (int pp = 0; pp < 2; ++pp) {       // 64 p-rows x 8 d-chunks of 8
    int s = pp * 256 + t;
    int p = s >> 3, dc = s & 7;
    bf16x8 v = *(const bf16x8*)(Vp + ((size_t)bh * KP + p0 + p) * 64 + dc * 8);
    *(bf16x8*)(tile + p * 72 + dc * 8) = v;
  }
  __syncthreads();
  for (int pp = 0; pp < 2; ++pp) {       // 64 d-rows x 8 p-chunks of 8
    int s = pp * 256 + t;
    int d = s >> 3, pc = s & 7;
    bf16x8 o;
    for (int j = 0; j < 8; ++j) o[j] = (short)tile[(pc * 8 + j) * 72 + d];
    *(bf16x8*)(VpT + ((size_t)bh * 64 + d) * KP + p0 + pc * 8) = o;
  }
}

// ---------------------------------------------------------------------------
// 7. Attention (unchanged this round)
__global__ __launch_bounds__(256) void attn_kernel(
    const unsigned short* __restrict__ Q, const unsigned short* __restrict__ Kp,
    const unsigned short* __restrict__ VpT, unsigned short* __restrict__ attnout) {
  __shared__ unsigned short P[64 * 328];
  const int tid = threadIdx.x;
  const int lane = tid & 63, w = tid >> 6;
  const int quad = lane >> 4, lcol = lane & 15;
  const int bx = blockIdx.x, by = blockIdx.y;
  const int q0 = bx * 64 + w * 16;

  bf16x8 aq[2];
  {
    int qr = q0 + lcol;
    if (qr < N_TOK) {
      const unsigned short* qp = Q + ((size_t)by * N_TOK + qr) * 64;
      aq[0] = *(const bf16x8*)(qp + quad * 8);
      aq[1] = *(const bf16x8*)(qp + 32 + quad * 8);
    } else {
      bf16x8 z = {0, 0, 0, 0, 0, 0, 0, 0};
      aq[0] = z; aq[1] = z;
    }
  }
  floatx4 sacc[20] = {};
  for (int nt = 0; nt < 20; ++nt) {
    const unsigned short* kp = Kp + ((size_t)by * KP + nt * 16 + lcol) * 64;
    bf16x8 b0 = *(const bf16x8*)(kp + quad * 8);
    bf16x8 b1 = *(const bf16x8*)(kp + 32 + quad * 8);
    sacc[nt] = __builtin_amdgcn_mfma_f32_16x16x32_bf16(aq[0], b0, sacc[nt], 0, 0, 0);
    sacc[nt] = __builtin_amdgcn_mfma_f32_16x16x32_bf16(aq[1], b1, sacc[nt], 0, 0, 0);
  }
  const float scale = 0.125f;
  for (int r = 0; r < 4; ++r) {
    float mx = -1e30f;
    for (int nt = 0; nt < 20; ++nt) {
      int n = nt * 16 + lcol;
      float s = sacc[nt][r] * scale;
      if (n < KEEP) mx = fmaxf(mx, s);
    }
    for (int off = 1; off < 16; off <<= 1) mx = fmaxf(mx, __shfl_xor(mx, off, 64));
    float sum = 0.f;
    for (int nt = 0; nt < 20; ++nt) {
      int n = nt * 16 + lcol;
      float e = (n < KEEP) ? __expf(sacc[nt][r] * scale - mx) : 0.f;
      sacc[nt][r] = e;
      sum += e;
    }
    for (int off = 1; off < 16; off <<= 1) sum += __shfl_xor(sum, off, 64);
    float inv = 1.f / sum;
    int rowl = w * 16 + quad * 4 + r;
    for (int nt = 0; nt < 20; ++nt)
      P[rowl * 328 + nt * 16 + lcol] = f2bf(sacc[nt][r] * inv);
  }
  __syncthreads();
  floatx4 oacc[4] = {};
  for (int kc = 0; kc < 10; ++kc) {
    bf16x8 pa = *(const bf16x8*)(P + (w * 16 + lcol) * 328 + kc * 32 + quad * 8);
    for (int nt = 0; nt < 4; ++nt) {
      bf16x8 vb = *(const bf16x8*)(VpT + ((size_t)by * 64 + nt * 16 + lcol) * KP + kc * 32 + quad * 8);
      oacc[nt] = __builtin_amdgcn_mfma_f32_16x16x32_bf16(pa, vb, oacc[nt], 0, 0, 0);
    }
  }
  int b = by / H_, h = by - b * H_;
  for (int nt = 0; nt < 4; ++nt)
    for (int r = 0; r < 4; ++r) {
      int qr = bx * 64 + w * 16 + quad * 4 + r;
      if (qr < N_TOK)
        attnout[((size_t)(b * N_TOK + qr)) * C_ + h * 64 + nt * 16 + lcol] = f2bf(oacc[nt][r]);
    }
}

// ---------------------------------------------------------------------------
// 8. Proj GEMM: same BK=64 swizzled core, fp32 out + bias
__global__ __launch_bounds__(256) void proj_gemm_kernel(
    const unsigned short* __restrict__ A, const unsigned short* __restrict__ Bt,
    const float* __restrict__ bias, float* __restrict__ out) {
  __shared__ unsigned short As[128 * 64];
  __shared__ unsigned short Bs[128 * 64];
  const int tid = threadIdx.x;
  const int lane = tid & 63, wv = tid >> 6;
  const int quad = lane >> 4, lcol = lane & 15;
  const int wm = wv & 1, wn = wv >> 1;
  int sid = blockIdx.x;
  int m_t, n_t;
  if (sid < 1728) {
    int sb = sid / 48, r = sid % 48;
    m_t = sb * 8 + (r & 7);
    n_t = r >> 3;
  } else { m_t = 288; n_t = sid - 1728; }
  const int m0 = m_t * 128, n0 = n_t * 128;
  const int swz = lcol & 7;

  floatx4 acc[4][4] = {};
  for (int k0 = 0; k0 < 768; k0 += 64) {
#pragma unroll
    for (int c = 0; c < 4; ++c) {
      int s = c * 256 + tid;
      int r = s >> 3, cs = s & 7;
      int gc = ((cs ^ (r & 7)) << 3);
      gl_lds16(A  + (size_t)(m0 + r) * 768 + k0 + gc, As + s * 8);
      gl_lds16(Bt + (size_t)(n0 + r) * 768 + k0 + gc, Bs + s * 8);
    }
    __syncthreads();
#pragma unroll
    for (int kh = 0; kh < 2; ++kh) {
      bf16x8 af[4], bfr[4];
      int cc = kh * 4 + quad;
#pragma unroll
      for (int i = 0; i < 4; ++i)
        af[i] = *(const bf16x8*)(As + (wm * 64 + i * 16 + lcol) * 64 + ((cc ^ swz) << 3));
#pragma unroll
      for (int i = 0; i < 4; ++i)
        bfr[i] = *(const bf16x8*)(Bs + (wn * 64 + i * 16 + lcol) * 64 + ((cc ^ swz) << 3));
#pragma unroll
      for (int i = 0; i < 4; ++i)
#pragma unroll
        for (int j = 0; j < 4; ++j)
          acc[i][j] = __builtin_amdgcn_mfma_f32_16x16x32_bf16(af[i], bfr[j], acc[i][j], 0, 0, 0);
    }
    __syncthreads();
  }
  const int nbase = n0 + wn * 64;
  float bv[4];
#pragma unroll
  for (int nt = 0; nt < 4; ++nt) bv[nt] = bias[nbase + nt * 16 + lcol];
#pragma unroll
  for (int mt = 0; mt < 4; ++mt)
#pragma unroll
    for (int r = 0; r < 4; ++r) {
      int m = m0 + wm * 64 + mt * 16 + quad * 4 + r;
      if (m >= M_ROWS) continue;
#pragma unroll
      for (int nt = 0; nt < 4; ++nt)
        out[(size_t)m * C_ + nbase + nt * 16 + lcol] = acc[mt][nt][r] + bv[nt];
    }
}

// ---------------------------------------------------------------------------
extern "C" void kernel_launch(void* const* d_in, const int* in_sizes, int n_in,
                              void* d_out, int out_size, void* d_ws, size_t ws_size,
                              hipStream_t stream) {
  const float* x     = (const float*)d_in[0];
  const float* mask  = (const float*)d_in[1];
  const float* Wqkv  = (const float*)d_in[2];
  const float* bqkv  = (const float*)d_in[3];
  const float* Wproj = (const float*)d_in[4];
  const float* bproj = (const float*)d_in[5];
  float* out = (float*)d_out;

  char* ws = (char*)d_ws;
  unsigned short* xb     = (unsigned short*)(ws);                  // 56,819,712
  unsigned short* attno  = xb;                                     // reuse
  unsigned short* WqkvT  = (unsigned short*)(ws + 56819712);       //  3,538,944
  unsigned short* WprojT = (unsigned short*)(ws + 60358656);       //  1,179,648
  int*            pos    = (int*)(ws + 61538304);                  //  1,772,544
  unsigned short* Qb     = (unsigned short*)(ws + 63310848);       // 56,721,408
  unsigned short* Kpb    = (unsigned short*)(ws + 120032256);      // 31,457,280
  unsigned short* Vpb    = (unsigned short*)(ws + 151489536);      // 31,457,280
  unsigned short* VpTb   = (unsigned short*)(ws + 182946816);      // 31,457,280

  hipLaunchKernelGGL(topk_kernel,     dim3(768),      dim3(576), 0, stream, mask, pos);
  hipLaunchKernelGGL(convx_kernel,    dim3(27744),    dim3(256), 0, stream, x, xb);
  hipLaunchKernelGGL(convwT_kernel,   dim3(36, 12),   dim3(256), 0, stream, Wqkv, WqkvT, 2304);
  hipLaunchKernelGGL(convwT_kernel,   dim3(12, 12),   dim3(256), 0, stream, Wproj, WprojT, 768);
  hipLaunchKernelGGL(zeropad_kernel,  dim3(5952),     dim3(256), 0, stream, Kpb, Vpb);
  hipLaunchKernelGGL(qkv_gemm_kernel, dim3(5202),     dim3(256), 0, stream, xb, WqkvT, bqkv, pos, Qb, Kpb, Vpb);
  hipLaunchKernelGGL(transv_kernel,   dim3(5, 768),   dim3(256), 0, stream, Vpb, VpTb);
  hipLaunchKernelGGL(attn_kernel,     dim3(10, 768),  dim3(256), 0, stream, Qb, Kpb, VpTb, attno);
  hipLaunchKernelGGL(proj_gemm_kernel,dim3(1734),     dim3(256), 0, stream, attno, WprojT, bproj, out);
}